// Round 12
// baseline (278.442 us; speedup 1.0000x reference)
//
#include <hip/hip_runtime.h>
#include <math.h>

#define NPIX 8192
#define KCB  4096
#define DH   32
#define DIN  192
#define PB   4          // pixels per k_main block: 2 in SGPR + 2 in VGPR
#define EPS  2e-3f      // top-2 gap flag threshold (f32 k-dependent err <= ~4e-5)

typedef float f2 __attribute__((ext_vector_type(2)));

// ---------------- prep: c2 tables + even/odd transposed codebook ----------------
// cbE[j][k2] = cb[2*k2][4j..4j+3], cbO[j][k2] = cb[2*k2+1][...]  (j=0..7, k2=0..2047)
__global__ void k_prep(const float* __restrict__ cb, double* __restrict__ c2d,
                       float* __restrict__ c2f, float4* __restrict__ cbE,
                       float4* __restrict__ cbO) {
  int k = blockIdx.x * 256 + threadIdx.x;   // grid 16
  const float4* rp = (const float4*)(cb + k * DH);
  float4* dst = (k & 1) ? cbO : cbE;
  const int k2 = k >> 1;
  double s = 0.0;
  #pragma unroll
  for (int j = 0; j < DH / 4; ++j) {
    float4 v = rp[j];
    dst[j * (KCB / 2) + k2] = v;
    s = fma((double)v.x, (double)v.x, s);
    s = fma((double)v.y, (double)v.y, s);
    s = fma((double)v.z, (double)v.z, s);
    s = fma((double)v.w, (double)v.w, s);
  }
  c2d[k] = s;
  c2f[k] = (float)s;
}

// ---------------- codebook passthrough ----------------
__global__ void k_copy(const float* __restrict__ src, float* __restrict__ dst) {
  int i = blockIdx.x * 256 + threadIdx.x;   // grid 512
  dst[i] = src[i];
}

// ---------------- raw = latent^T @ wv_w^T + wv_b (f32) + x2 ----------------
__global__ __launch_bounds__(256) void k_raw(const float* __restrict__ latent,
    const float* __restrict__ wv_w, const float* __restrict__ wv_b,
    float* __restrict__ raw_out, float* __restrict__ x2_out) {
  __shared__ float wv[DH * 193];  // padded: conflict-free broadcast
  for (int idx = threadIdx.x; idx < DH * DIN; idx += 256) {
    int o = idx / DIN, i = idx - o * DIN;
    wv[o * 193 + i] = wv_w[idx];
  }
  __syncthreads();
  const int p = blockIdx.x * 8 + (threadIdx.x >> 5);  // pixel
  const int o = threadIdx.x & 31;
  const int b = p >> 10, hw = p & 1023;
  const float* lp = latent + b * (DIN * 1024) + hw;   // stride 1024 over channel
  float acc = wv_b[o];
  #pragma unroll 8
  for (int i = 0; i < DIN; ++i) acc = fmaf(lp[i * 1024], wv[o * 193 + i], acc);
  raw_out[p * DH + o] = acc;
  float s = acc * acc;
  #pragma unroll
  for (int m = 16; m; m >>= 1) s += __shfl_xor(s, m, 64);
  if (o == 0) x2_out[p] = s;
}

// monotone f32->u32 map packed with ~idx: u64 max == (max val, min idx)
__device__ inline unsigned long long packkey(float v, int idx) {
  unsigned int u = __float_as_uint(v);
  u = (u & 0x80000000u) ? ~u : (u | 0x80000000u);
  return ((unsigned long long)u << 32) | (unsigned int)(~idx);
}

__device__ inline float rfl(float x) {   // force wave-uniform (SGPR) value
  return __uint_as_float(__builtin_amdgcn_readfirstlane(__float_as_uint(x)));
}

// ---------------- main (f32): logits + top1(+top2 gap) + quantized ----------------
// grid 2048, block 256: 4 pixels/block; thread owns k-PAIR {2*k2, 2*k2+1},
// k2 = c*256 + tid, c = 0..7.  raw: px 0-1 SGPR, px 2-3 VGPR.  No LDS hot loop.
__global__ __launch_bounds__(256) void k_main(
    const float* __restrict__ raw_g, const float* __restrict__ x2_g,
    const float4* __restrict__ cbE, const float4* __restrict__ cbO,
    const float* __restrict__ cb, const float* __restrict__ c2f,
    const float* __restrict__ gumbel,
    const float* __restrict__ temp1p, const int* __restrict__ tempp,
    float* __restrict__ logit_out, float* __restrict__ code_out,
    float* __restrict__ true_out, float* __restrict__ quant_out,
    int* __restrict__ flags) {
  __shared__ unsigned long long redk[2][PB][4];
  __shared__ float              redb[2][2][PB][4];  // [path][b1/b2][p][wave]
  __shared__ int code_s[PB];

  const int tid  = threadIdx.x;
  const int pix0 = blockIdx.x * PB;

  // pixels 0,1: raw -> wave-uniform scalars (SGPRs)
  float sr[2][DH];
  #pragma unroll
  for (int p = 0; p < 2; ++p)
    #pragma unroll
    for (int d = 0; d < DH; ++d)
      sr[p][d] = rfl(raw_g[(pix0 + p) * DH + d]);

  // pixels 2,3: raw -> per-thread VGPR copies
  float vr[2][DH];
  #pragma unroll
  for (int p = 0; p < 2; ++p)
    #pragma unroll
    for (int j = 0; j < DH / 4; ++j) {
      float4 t = *(const float4*)&raw_g[(pix0 + 2 + p) * DH + 4 * j];
      asm("" : "+v"(t.x), "+v"(t.y), "+v"(t.z), "+v"(t.w));
      vr[p][4 * j + 0] = t.x; vr[p][4 * j + 1] = t.y;
      vr[p][4 * j + 2] = t.z; vr[p][4 * j + 3] = t.w;
    }

  const float inv_tt = rfl((float)(1.0 / ((double)(*temp1p) * (double)(*tempp))));
  float x2r[PB];
  int   rb[PB];
  #pragma unroll
  for (int p = 0; p < PB; ++p) {
    x2r[p] = rfl(x2_g[pix0 + p]);
    rb[p]  = (pix0 + p) * KCB;
  }

  float bl[PB], bl2[PB], bg[PB], bg2[PB];
  int   bli[PB], bgi[PB];
  #pragma unroll
  for (int p = 0; p < PB; ++p) {
    bl[p] = -INFINITY; bl2[p] = -INFINITY;
    bg[p] = -INFINITY; bg2[p] = -INFINITY;
    bli[p] = 0; bgi[p] = 0;
  }

  // pipeline: gumbel(f2) + c2(f2) for current iter, loaded one iter ahead
  f2 gfc[PB], gfn[PB];
  f2 c2c, c2n;
  c2c = *(const f2*)&c2f[2 * tid];
  #pragma unroll
  for (int p = 0; p < PB; ++p) gfc[p] = *(const f2*)&gumbel[rb[p] + 2 * tid];

  #pragma unroll 1
  for (int c = 0; c < 8; ++c) {
    const int k2 = c * 256 + tid;            // k-pair index, ascending over c
    const int k  = 2 * k2;

    if (c < 7) {                             // next iter's streams in flight
      c2n = *(const f2*)&c2f[k + 512];
      #pragma unroll
      for (int p = 0; p < PB; ++p) gfn[p] = *(const f2*)&gumbel[rb[p] + k + 512];
    }

    float da[PB], db[PB];
    #pragma unroll
    for (int p = 0; p < PB; ++p) { da[p] = 0.f; db[p] = 0.f; }

    #pragma unroll
    for (int j = 0; j < 8; ++j) {
      float4 ce = cbE[j * (KCB / 2) + k2];   // lane-contiguous 1KB/inst
      float4 co = cbO[j * (KCB / 2) + k2];
      da[0] = fmaf(ce.x, sr[0][4 * j + 0], da[0]);
      da[0] = fmaf(ce.y, sr[0][4 * j + 1], da[0]);
      da[0] = fmaf(ce.z, sr[0][4 * j + 2], da[0]);
      da[0] = fmaf(ce.w, sr[0][4 * j + 3], da[0]);
      da[1] = fmaf(ce.x, sr[1][4 * j + 0], da[1]);
      da[1] = fmaf(ce.y, sr[1][4 * j + 1], da[1]);
      da[1] = fmaf(ce.z, sr[1][4 * j + 2], da[1]);
      da[1] = fmaf(ce.w, sr[1][4 * j + 3], da[1]);
      da[2] = fmaf(ce.x, vr[0][4 * j + 0], da[2]);
      da[2] = fmaf(ce.y, vr[0][4 * j + 1], da[2]);
      da[2] = fmaf(ce.z, vr[0][4 * j + 2], da[2]);
      da[2] = fmaf(ce.w, vr[0][4 * j + 3], da[2]);
      da[3] = fmaf(ce.x, vr[1][4 * j + 0], da[3]);
      da[3] = fmaf(ce.y, vr[1][4 * j + 1], da[3]);
      da[3] = fmaf(ce.z, vr[1][4 * j + 2], da[3]);
      da[3] = fmaf(ce.w, vr[1][4 * j + 3], da[3]);
      db[0] = fmaf(co.x, sr[0][4 * j + 0], db[0]);
      db[0] = fmaf(co.y, sr[0][4 * j + 1], db[0]);
      db[0] = fmaf(co.z, sr[0][4 * j + 2], db[0]);
      db[0] = fmaf(co.w, sr[0][4 * j + 3], db[0]);
      db[1] = fmaf(co.x, sr[1][4 * j + 0], db[1]);
      db[1] = fmaf(co.y, sr[1][4 * j + 1], db[1]);
      db[1] = fmaf(co.z, sr[1][4 * j + 2], db[1]);
      db[1] = fmaf(co.w, sr[1][4 * j + 3], db[1]);
      db[2] = fmaf(co.x, vr[0][4 * j + 0], db[2]);
      db[2] = fmaf(co.y, vr[0][4 * j + 1], db[2]);
      db[2] = fmaf(co.z, vr[0][4 * j + 2], db[2]);
      db[2] = fmaf(co.w, vr[0][4 * j + 3], db[2]);
      db[3] = fmaf(co.x, vr[1][4 * j + 0], db[3]);
      db[3] = fmaf(co.y, vr[1][4 * j + 1], db[3]);
      db[3] = fmaf(co.z, vr[1][4 * j + 2], db[3]);
      db[3] = fmaf(co.w, vr[1][4 * j + 3], db[3]);
    }

    #pragma unroll
    for (int p = 0; p < PB; ++p) {
      float va = fmaf(2.f, da[p], -(x2r[p] + c2c.x));   // k even (same formula as before)
      float vb = fmaf(2.f, db[p], -(x2r[p] + c2c.y));   // k odd
      f2 st; st.x = va; st.y = vb;
      __builtin_nontemporal_store(st, (f2*)&logit_out[rb[p] + k]);
      // logit path: pairwise max (>= picks even/earlier k), then top-2 update
      bool ae = va >= vb;
      float hi = ae ? va : vb, lo = ae ? vb : va;
      int   ih = k + (ae ? 0 : 1);
      bool bt = hi > bl[p];
      bl2[p] = bt ? fmaxf(bl[p], lo) : fmaxf(bl2[p], hi);
      bli[p] = bt ? ih : bli[p];
      bl[p]  = bt ? hi : bl[p];
      // gumbel path
      float za = fmaf(va, inv_tt, gfc[p].x);
      float zb = fmaf(vb, inv_tt, gfc[p].y);
      bool ze = za >= zb;
      float zh = ze ? za : zb, zl = ze ? zb : za;
      int   iz = k + (ze ? 0 : 1);
      bool gt = zh > bg[p];
      bg2[p] = gt ? fmaxf(bg[p], zl) : fmaxf(bg2[p], zh);
      bgi[p] = gt ? iz : bgi[p];
      bg[p]  = gt ? zh : bg[p];
    }

    c2c = c2n;
    #pragma unroll
    for (int p = 0; p < PB; ++p) gfc[p] = gfn[p];
  }

  // block reduction: 64-lane butterfly of (top1-key, top1-val, top2-val), then LDS
  const int wave = tid >> 6;
  const int lane = tid & 63;
  #pragma unroll
  for (int p = 0; p < PB; ++p) {
    unsigned long long kl = packkey(bl[p], bli[p]);
    unsigned long long kg = packkey(bg[p], bgi[p]);
    float b1l = bl[p], b2l = bl2[p], b1g = bg[p], b2g = bg2[p];
    #pragma unroll
    for (int m = 32; m; m >>= 1) {
      unsigned long long o1 = __shfl_xor(kl, m, 64);
      float ob1 = __shfl_xor(b1l, m, 64), ob2 = __shfl_xor(b2l, m, 64);
      b2l = fmaxf(fmaxf(b2l, ob2), fminf(b1l, ob1));
      b1l = fmaxf(b1l, ob1);
      if (o1 > kl) kl = o1;
      unsigned long long o2 = __shfl_xor(kg, m, 64);
      float og1 = __shfl_xor(b1g, m, 64), og2 = __shfl_xor(b2g, m, 64);
      b2g = fmaxf(fmaxf(b2g, og2), fminf(b1g, og1));
      b1g = fmaxf(b1g, og1);
      if (o2 > kg) kg = o2;
    }
    if (lane == 0) {
      redk[0][p][wave] = kl;  redk[1][p][wave] = kg;
      redb[0][0][p][wave] = b1l; redb[0][1][p][wave] = b2l;
      redb[1][0][p][wave] = b1g; redb[1][1][p][wave] = b2g;
    }
  }
  __syncthreads();
  if (tid < PB) {
    const int p = tid;
    unsigned long long kl = redk[0][p][0], kg = redk[1][p][0];
    float b1l = redb[0][0][p][0], b2l = redb[0][1][p][0];
    float b1g = redb[1][0][p][0], b2g = redb[1][1][p][0];
    #pragma unroll
    for (int w2 = 1; w2 < 4; ++w2) {
      if (redk[0][p][w2] > kl) kl = redk[0][p][w2];
      if (redk[1][p][w2] > kg) kg = redk[1][p][w2];
      b2l = fmaxf(fmaxf(b2l, redb[0][1][p][w2]), fminf(b1l, redb[0][0][p][w2]));
      b1l = fmaxf(b1l, redb[0][0][p][w2]);
      b2g = fmaxf(fmaxf(b2g, redb[1][1][p][w2]), fminf(b1g, redb[1][0][p][w2]));
      b1g = fmaxf(b1g, redb[1][0][p][w2]);
    }
    int ti = (int)(~(unsigned int)kl);
    int ci = (int)(~(unsigned int)kg);
    true_out[pix0 + p] = (float)ti;
    code_out[pix0 + p] = (float)ci;
    code_s[p] = ci;
    flags[pix0 + p] = (b1l - b2l < EPS || b1g - b2g < EPS) ? 1 : 0;
  }
  __syncthreads();
  if (tid < PB * DH)
    quant_out[pix0 * DH + tid] = cb[code_s[tid >> 5] * DH + (tid & 31)];
}

// ---------------- refine (exact f64, flagged pixels only; rare) ----------------
__global__ __launch_bounds__(256) void k_refine(
    const float* __restrict__ latent, const float* __restrict__ wv_w,
    const float* __restrict__ wv_b, const float* __restrict__ cb,
    const double* __restrict__ c2d, const float* __restrict__ gumbel,
    const float* __restrict__ temp1p, const int* __restrict__ tempp,
    float* __restrict__ code_out, float* __restrict__ true_out,
    float* __restrict__ quant_out, const int* __restrict__ flags) {
  const int pix = blockIdx.x;
  if (flags[pix] == 0) return;

  __shared__ double part[DH][8];
  __shared__ double rawd[DH];
  __shared__ double x2sh;
  __shared__ double redv[2][4];
  __shared__ int    redi[2][4];
  __shared__ int    ig_sh;
  const int tid = threadIdx.x;
  const int b = pix >> 10, hw = pix & 1023;

  {
    const int o = tid >> 3, pt = tid & 7;
    const float* lp = latent + b * (DIN * 1024) + hw;
    double acc = 0.0;
    #pragma unroll 4
    for (int i = pt * 24; i < pt * 24 + 24; ++i)
      acc = fma((double)lp[i * 1024], (double)wv_w[o * DIN + i], acc);
    part[o][pt] = acc;
  }
  __syncthreads();
  if (tid < DH) {
    double acc = (double)wv_b[tid];
    #pragma unroll
    for (int j = 0; j < 8; ++j) acc += part[tid][j];
    rawd[tid] = acc;
  }
  __syncthreads();
  if (tid == 0) {
    double s = 0.0;
    #pragma unroll
    for (int d = 0; d < DH; ++d) s = fma(rawd[d], rawd[d], s);
    x2sh = s;
  }
  __syncthreads();

  const double tt  = (double)(*temp1p) * (double)(*tempp);
  const double tau = sqrt((double)(*tempp));
  const double x2  = x2sh;

  double bl = -INFINITY, bg = -INFINITY;
  int il = 0, ig = 0;
  for (int c = 0; c < KCB / 256; ++c) {
    const int k = c * 256 + tid;
    const float4* rp = (const float4*)(cb + k * DH);
    double dot = 0.0;
    #pragma unroll
    for (int j = 0; j < DH / 4; ++j) {
      float4 v = rp[j];
      dot = fma((double)v.x, rawd[4 * j + 0], dot);
      dot = fma((double)v.y, rawd[4 * j + 1], dot);
      dot = fma((double)v.z, rawd[4 * j + 2], dot);
      dot = fma((double)v.w, rawd[4 * j + 3], dot);
    }
    double lraw = -((x2 + c2d[k]) - 2.0 * dot);
    double zt = lraw / tt;
    if (zt > bl) { bl = zt; il = k; }
    double zg = (zt + (double)gumbel[(long long)pix * KCB + k]) / tau;
    if (zg > bg) { bg = zg; ig = k; }
  }

  const int wave = tid >> 6, lane = tid & 63;
  #pragma unroll
  for (int m = 32; m; m >>= 1) {
    double ov = __shfl_xor(bl, m, 64); int oi = __shfl_xor(il, m, 64);
    if (ov > bl || (ov == bl && oi < il)) { bl = ov; il = oi; }
    double og = __shfl_xor(bg, m, 64); int oj = __shfl_xor(ig, m, 64);
    if (og > bg || (og == bg && oj < ig)) { bg = og; ig = oj; }
  }
  if (lane == 0) { redv[0][wave] = bl; redi[0][wave] = il;
                   redv[1][wave] = bg; redi[1][wave] = ig; }
  __syncthreads();
  if (tid == 0) {
    double vl = redv[0][0], vg = redv[1][0];
    int    jl = redi[0][0], jg = redi[1][0];
    for (int w2 = 1; w2 < 4; ++w2) {
      if (redv[0][w2] > vl || (redv[0][w2] == vl && redi[0][w2] < jl)) { vl = redv[0][w2]; jl = redi[0][w2]; }
      if (redv[1][w2] > vg || (redv[1][w2] == vg && redi[1][w2] < jg)) { vg = redv[1][w2]; jg = redi[1][w2]; }
    }
    true_out[pix] = (float)jl;
    code_out[pix] = (float)jg;
    ig_sh = jg;
  }
  __syncthreads();
  if (tid < DH) quant_out[pix * DH + tid] = cb[ig_sh * DH + tid];
}

// ---------------- hard = quantized @ wq_w^T + wq_b, NCHW out ----------------
__global__ __launch_bounds__(256) void k_hard(const float* __restrict__ quant,
    const float* __restrict__ wq_w, const float* __restrict__ wq_b,
    float* __restrict__ hard) {
  __shared__ float wq[DIN * DH];
  __shared__ float qs[32][33];
  const int bh = blockIdx.x;       // b*32 + h
  const int b = bh >> 5, h = bh & 31;
  for (int idx = threadIdx.x; idx < DIN * DH; idx += 256) wq[idx] = wq_w[idx];
  for (int idx = threadIdx.x; idx < 32 * DH; idx += 256)
    qs[idx >> 5][idx & 31] = quant[bh * (32 * DH) + idx];
  __syncthreads();
  for (int it = 0; it < (DIN * 32) / 256; ++it) {
    const int idx = it * 256 + threadIdx.x;
    const int o = idx >> 5, w = idx & 31;
    float acc = wq_b[o];
    #pragma unroll
    for (int d = 0; d < DH; ++d) acc = fmaf(qs[w][d], wq[o * DH + d], acc);
    hard[((b * DIN + o) * 32 + h) * 32 + w] = acc;
  }
}

extern "C" void kernel_launch(void* const* d_in, const int* in_sizes, int n_in,
                              void* d_out, int out_size, void* d_ws, size_t ws_size,
                              hipStream_t stream) {
  const float* latent      = (const float*)d_in[0];
  const float* cb          = (const float*)d_in[1];
  const float* wv_w        = (const float*)d_in[2];
  const float* wv_b        = (const float*)d_in[3];
  const float* wq_w        = (const float*)d_in[4];
  const float* wq_b        = (const float*)d_in[5];
  const float* temp1       = (const float*)d_in[6];
  const float* gumbel      = (const float*)d_in[7];
  const int*   temperature = (const int*)d_in[8];

  float* out      = (float*)d_out;
  float* hard     = out;                 // 1572864
  float* code     = out + 1572864;       // 8192
  float* true_c   = out + 1581056;       // 8192
  float* logitRaw = out + 1589248;       // 33554432
  float* raw      = out + 35143680;      // 262144
  float* quant    = out + 35405824;      // 262144
  float* cb_out   = out + 35668096;      // 131072

  char*   ws    = (char*)d_ws;
  double* c2d   = (double*)ws;                    // 32 KB @ 0
  float*  c2f   = (float*)(ws + 32768);           // 16 KB
  int*    flags = (int*)(ws + 49152);             // 32 KB
  float*  x2f   = (float*)(ws + 81920);           // 32 KB
  float4* cbE   = (float4*)(ws + 131072);         // 256 KB @ 128K
  float4* cbO   = (float4*)(ws + 393216);         // 256 KB @ 384K

  k_prep<<<KCB / 256, 256, 0, stream>>>(cb, c2d, c2f, cbE, cbO);
  k_copy<<<(KCB * DH) / 256, 256, 0, stream>>>(cb, cb_out);
  k_raw <<<NPIX / 8, 256, 0, stream>>>(latent, wv_w, wv_b, raw, x2f);
  k_main<<<NPIX / PB, 256, 0, stream>>>(raw, x2f, cbE, cbO, cb, c2f, gumbel,
                                        temp1, temperature, logitRaw,
                                        code, true_c, quant, flags);
  k_refine<<<NPIX, 256, 0, stream>>>(latent, wv_w, wv_b, cb, c2d, gumbel,
                                     temp1, temperature, code, true_c, quant, flags);
  k_hard<<<8 * 32, 256, 0, stream>>>(quant, wq_w, wq_b, hard);
}

// Round 13
// 156.654 us; speedup vs baseline: 1.7774x; 1.7774x over previous
//
#include <hip/hip_runtime.h>
#include <math.h>

#define NPIX 8192
#define KCB  4096
#define DH   32
#define DIN  192
#define PB   4          // pixels per k_main block: 2 in SGPR + 2 in VGPR
#define EPS  2e-3f      // top-2 gap flag threshold (f32 k-dependent err <= ~4e-5)

// ---------------- prep: c2 tables + transposed codebook cbT4[8][4096] ----------------
__global__ void k_prep(const float* __restrict__ cb, double* __restrict__ c2d,
                       float* __restrict__ c2f, float4* __restrict__ cbT4) {
  int k = blockIdx.x * 256 + threadIdx.x;   // grid 16
  const float4* rp = (const float4*)(cb + k * DH);
  double s = 0.0;
  #pragma unroll
  for (int j = 0; j < DH / 4; ++j) {
    float4 v = rp[j];
    cbT4[j * KCB + k] = v;                  // coalesced transposed store
    s = fma((double)v.x, (double)v.x, s);
    s = fma((double)v.y, (double)v.y, s);
    s = fma((double)v.z, (double)v.z, s);
    s = fma((double)v.w, (double)v.w, s);
  }
  c2d[k] = s;
  c2f[k] = (float)s;
}

// ---------------- codebook passthrough ----------------
__global__ void k_copy(const float* __restrict__ src, float* __restrict__ dst) {
  int i = blockIdx.x * 256 + threadIdx.x;   // grid 512
  dst[i] = src[i];
}

// ---------------- raw = latent^T @ wv_w^T + wv_b (f32) + x2 ----------------
__global__ __launch_bounds__(256) void k_raw(const float* __restrict__ latent,
    const float* __restrict__ wv_w, const float* __restrict__ wv_b,
    float* __restrict__ raw_out, float* __restrict__ x2_out) {
  __shared__ float wv[DH * 193];  // padded: conflict-free broadcast
  for (int idx = threadIdx.x; idx < DH * DIN; idx += 256) {
    int o = idx / DIN, i = idx - o * DIN;
    wv[o * 193 + i] = wv_w[idx];
  }
  __syncthreads();
  const int p = blockIdx.x * 8 + (threadIdx.x >> 5);  // pixel
  const int o = threadIdx.x & 31;
  const int b = p >> 10, hw = p & 1023;
  const float* lp = latent + b * (DIN * 1024) + hw;   // stride 1024 over channel
  float acc = wv_b[o];
  #pragma unroll 8
  for (int i = 0; i < DIN; ++i) acc = fmaf(lp[i * 1024], wv[o * 193 + i], acc);
  raw_out[p * DH + o] = acc;
  float s = acc * acc;
  #pragma unroll
  for (int m = 16; m; m >>= 1) s += __shfl_xor(s, m, 64);
  if (o == 0) x2_out[p] = s;
}

// monotone f32->u32 map packed with ~idx: u64 max == (max val, min idx)
__device__ inline unsigned long long packkey(float v, int idx) {
  unsigned int u = __float_as_uint(v);
  u = (u & 0x80000000u) ? ~u : (u | 0x80000000u);
  return ((unsigned long long)u << 32) | (unsigned int)(~idx);
}

__device__ inline float rfl(float x) {   // force wave-uniform (SGPR) value
  return __uint_as_float(__builtin_amdgcn_readfirstlane(__float_as_uint(x)));
}

// ---------------- main (f32): SPLIT-K logits + per-half top-2 partials ----------------
// grid 4096 = (NPIX/PB) * 2 halves; block: 4 pixels x 2048 k.
// thread owns row k = half*2048 + c*256 + tid, c = 0..7.
// raw: px 0-1 SGPR, px 2-3 VGPR. cbT4 lane-contiguous. No LDS hot loop.
__global__ __launch_bounds__(256) void k_main(
    const float* __restrict__ raw_g, const float* __restrict__ x2_g,
    const float4* __restrict__ cbT4, const float* __restrict__ c2f,
    const float* __restrict__ gumbel,
    const float* __restrict__ temp1p, const int* __restrict__ tempp,
    float* __restrict__ logit_out,
    float4* __restrict__ pl, int2* __restrict__ pi) {
  __shared__ unsigned long long redk[2][PB][4];
  __shared__ float              redb[2][2][PB][4];  // [path][b1/b2][p][wave]

  const int tid   = threadIdx.x;
  const int half  = blockIdx.x & 1;
  const int pix0  = (blockIdx.x >> 1) * PB;
  const int kbase = half * (KCB / 2);

  // pixels 0,1: raw -> wave-uniform scalars (SGPRs)
  float sr[2][DH];
  #pragma unroll
  for (int p = 0; p < 2; ++p)
    #pragma unroll
    for (int d = 0; d < DH; ++d)
      sr[p][d] = rfl(raw_g[(pix0 + p) * DH + d]);

  // pixels 2,3: raw -> per-thread VGPR copies
  float vr[2][DH];
  #pragma unroll
  for (int p = 0; p < 2; ++p)
    #pragma unroll
    for (int j = 0; j < DH / 4; ++j) {
      float4 t = *(const float4*)&raw_g[(pix0 + 2 + p) * DH + 4 * j];
      asm("" : "+v"(t.x), "+v"(t.y), "+v"(t.z), "+v"(t.w));
      vr[p][4 * j + 0] = t.x; vr[p][4 * j + 1] = t.y;
      vr[p][4 * j + 2] = t.z; vr[p][4 * j + 3] = t.w;
    }

  const float inv_tt = rfl((float)(1.0 / ((double)(*temp1p) * (double)(*tempp))));
  float x2r[PB];
  int   rb[PB];
  #pragma unroll
  for (int p = 0; p < PB; ++p) {
    x2r[p] = rfl(x2_g[pix0 + p]);
    rb[p]  = (pix0 + p) * KCB;
  }

  float bl[PB], bl2[PB], bg[PB], bg2[PB];
  int   bli[PB], bgi[PB];
  #pragma unroll
  for (int p = 0; p < PB; ++p) {
    bl[p] = -INFINITY; bl2[p] = -INFINITY;
    bg[p] = -INFINITY; bg2[p] = -INFINITY;
    bli[p] = 0; bgi[p] = 0;
  }

  // pipeline: gumbel + c2 for current chunk, loaded one chunk ahead
  float gfc[PB], gfn[PB];
  float c2c, c2n;
  c2c = c2f[kbase + tid];
  #pragma unroll
  for (int p = 0; p < PB; ++p) gfc[p] = gumbel[rb[p] + kbase + tid];

  #pragma unroll 1
  for (int c = 0; c < 8; ++c) {
    const int k = kbase + c * 256 + tid;       // per-thread k ascending over c

    if (c < 7) {                               // next chunk's streams in flight
      c2n = c2f[k + 256];
      #pragma unroll
      for (int p = 0; p < PB; ++p) gfn[p] = gumbel[rb[p] + k + 256];
    }

    float4 cv[8];
    #pragma unroll
    for (int j = 0; j < 8; ++j) cv[j] = cbT4[j * KCB + k];  // lane-contiguous 1KB/inst

    float dots[PB];
    #pragma unroll
    for (int p = 0; p < PB; ++p) dots[p] = 0.f;
    #pragma unroll
    for (int j = 0; j < 8; ++j) {
      dots[0] = fmaf(cv[j].x, sr[0][4 * j + 0], dots[0]);
      dots[0] = fmaf(cv[j].y, sr[0][4 * j + 1], dots[0]);
      dots[0] = fmaf(cv[j].z, sr[0][4 * j + 2], dots[0]);
      dots[0] = fmaf(cv[j].w, sr[0][4 * j + 3], dots[0]);
      dots[1] = fmaf(cv[j].x, sr[1][4 * j + 0], dots[1]);
      dots[1] = fmaf(cv[j].y, sr[1][4 * j + 1], dots[1]);
      dots[1] = fmaf(cv[j].z, sr[1][4 * j + 2], dots[1]);
      dots[1] = fmaf(cv[j].w, sr[1][4 * j + 3], dots[1]);
      dots[2] = fmaf(cv[j].x, vr[0][4 * j + 0], dots[2]);
      dots[2] = fmaf(cv[j].y, vr[0][4 * j + 1], dots[2]);
      dots[2] = fmaf(cv[j].z, vr[0][4 * j + 2], dots[2]);
      dots[2] = fmaf(cv[j].w, vr[0][4 * j + 3], dots[2]);
      dots[3] = fmaf(cv[j].x, vr[1][4 * j + 0], dots[3]);
      dots[3] = fmaf(cv[j].y, vr[1][4 * j + 1], dots[3]);
      dots[3] = fmaf(cv[j].z, vr[1][4 * j + 2], dots[3]);
      dots[3] = fmaf(cv[j].w, vr[1][4 * j + 3], dots[3]);
    }

    #pragma unroll
    for (int p = 0; p < PB; ++p) {
      float v = fmaf(2.f, dots[p], -(x2r[p] + c2c));
      __builtin_nontemporal_store(v, &logit_out[rb[p] + k]);
      bool bt = v > bl[p];
      bl2[p] = bt ? bl[p] : fmaxf(bl2[p], v);
      bli[p] = bt ? k : bli[p];
      bl[p]  = bt ? v : bl[p];
      float z = fmaf(v, inv_tt, gfc[p]);
      bool gt = z > bg[p];
      bg2[p] = gt ? bg[p] : fmaxf(bg2[p], z);
      bgi[p] = gt ? k : bgi[p];
      bg[p]  = gt ? z : bg[p];
    }

    c2c = c2n;
    #pragma unroll
    for (int p = 0; p < PB; ++p) gfc[p] = gfn[p];
  }

  // block reduction: 64-lane butterfly of (top1-key, top1-val, top2-val), then LDS
  const int wave = tid >> 6;
  const int lane = tid & 63;
  #pragma unroll
  for (int p = 0; p < PB; ++p) {
    unsigned long long kl = packkey(bl[p], bli[p]);
    unsigned long long kg = packkey(bg[p], bgi[p]);
    float b1l = bl[p], b2l = bl2[p], b1g = bg[p], b2g = bg2[p];
    #pragma unroll
    for (int m = 32; m; m >>= 1) {
      unsigned long long o1 = __shfl_xor(kl, m, 64);
      float ob1 = __shfl_xor(b1l, m, 64), ob2 = __shfl_xor(b2l, m, 64);
      b2l = fmaxf(fmaxf(b2l, ob2), fminf(b1l, ob1));
      b1l = fmaxf(b1l, ob1);
      if (o1 > kl) kl = o1;
      unsigned long long o2 = __shfl_xor(kg, m, 64);
      float og1 = __shfl_xor(b1g, m, 64), og2 = __shfl_xor(b2g, m, 64);
      b2g = fmaxf(fmaxf(b2g, og2), fminf(b1g, og1));
      b1g = fmaxf(b1g, og1);
      if (o2 > kg) kg = o2;
    }
    if (lane == 0) {
      redk[0][p][wave] = kl;  redk[1][p][wave] = kg;
      redb[0][0][p][wave] = b1l; redb[0][1][p][wave] = b2l;
      redb[1][0][p][wave] = b1g; redb[1][1][p][wave] = b2g;
    }
  }
  __syncthreads();
  if (tid < PB) {
    const int p = tid;
    unsigned long long kl = redk[0][p][0], kg = redk[1][p][0];
    float b1l = redb[0][0][p][0], b2l = redb[0][1][p][0];
    float b1g = redb[1][0][p][0], b2g = redb[1][1][p][0];
    #pragma unroll
    for (int w2 = 1; w2 < 4; ++w2) {
      if (redk[0][p][w2] > kl) kl = redk[0][p][w2];
      if (redk[1][p][w2] > kg) kg = redk[1][p][w2];
      b2l = fmaxf(fmaxf(b2l, redb[0][1][p][w2]), fminf(b1l, redb[0][0][p][w2]));
      b1l = fmaxf(b1l, redb[0][0][p][w2]);
      b2g = fmaxf(fmaxf(b2g, redb[1][1][p][w2]), fminf(b1g, redb[1][0][p][w2]));
      b1g = fmaxf(b1g, redb[1][0][p][w2]);
    }
    int ti = (int)(~(unsigned int)kl);
    int ci = (int)(~(unsigned int)kg);
    const int idx = (pix0 + p) * 2 + half;
    pl[idx] = make_float4(b1l, b2l, b1g, b2g);
    pi[idx] = make_int2(ti, ci);
  }
}

// ---------------- merge halves: code/trueCode/flags + quant gather ----------------
// grid 1024, block 256: 8 pixels/block, 32 lanes per pixel
__global__ __launch_bounds__(256) void k_merge(
    const float4* __restrict__ pl, const int2* __restrict__ pi,
    const float* __restrict__ cb,
    float* __restrict__ code_out, float* __restrict__ true_out,
    float* __restrict__ quant_out, int* __restrict__ flags) {
  __shared__ int code_s[8];
  const int tid  = threadIdx.x;
  const int grp  = tid >> 5, lane = tid & 31;
  const int pix  = blockIdx.x * 8 + grp;
  if (lane == 0) {
    float4 a = pl[pix * 2 + 0];     // half 0: lower k indices
    float4 b = pl[pix * 2 + 1];     // half 1
    int2  ia = pi[pix * 2 + 0];
    int2  ib = pi[pix * 2 + 1];
    // logit path: strict > so half 0 wins exact ties (lower k = first occurrence)
    float b2l = fmaxf(fmaxf(a.y, b.y), fminf(a.x, b.x));
    float b1l = a.x; int il = ia.x;
    if (b.x > b1l) { b1l = b.x; il = ib.x; }
    // gumbel path
    float b2g = fmaxf(fmaxf(a.w, b.w), fminf(a.z, b.z));
    float b1g = a.z; int ig = ia.y;
    if (b.z > b1g) { b1g = b.z; ig = ib.y; }
    true_out[pix] = (float)il;
    code_out[pix] = (float)ig;
    flags[pix] = (b1l - b2l < EPS || b1g - b2g < EPS) ? 1 : 0;
    code_s[grp] = ig;
  }
  __syncthreads();
  quant_out[pix * DH + lane] = cb[code_s[grp] * DH + lane];
}

// ---------------- refine (exact f64, flagged pixels only; rare) ----------------
__global__ __launch_bounds__(256) void k_refine(
    const float* __restrict__ latent, const float* __restrict__ wv_w,
    const float* __restrict__ wv_b, const float* __restrict__ cb,
    const double* __restrict__ c2d, const float* __restrict__ gumbel,
    const float* __restrict__ temp1p, const int* __restrict__ tempp,
    float* __restrict__ code_out, float* __restrict__ true_out,
    float* __restrict__ quant_out, const int* __restrict__ flags) {
  const int pix = blockIdx.x;
  if (flags[pix] == 0) return;

  __shared__ double part[DH][8];
  __shared__ double rawd[DH];
  __shared__ double x2sh;
  __shared__ double redv[2][4];
  __shared__ int    redi[2][4];
  __shared__ int    ig_sh;
  const int tid = threadIdx.x;
  const int b = pix >> 10, hw = pix & 1023;

  {
    const int o = tid >> 3, pt = tid & 7;
    const float* lp = latent + b * (DIN * 1024) + hw;
    double acc = 0.0;
    #pragma unroll 4
    for (int i = pt * 24; i < pt * 24 + 24; ++i)
      acc = fma((double)lp[i * 1024], (double)wv_w[o * DIN + i], acc);
    part[o][pt] = acc;
  }
  __syncthreads();
  if (tid < DH) {
    double acc = (double)wv_b[tid];
    #pragma unroll
    for (int j = 0; j < 8; ++j) acc += part[tid][j];
    rawd[tid] = acc;
  }
  __syncthreads();
  if (tid == 0) {
    double s = 0.0;
    #pragma unroll
    for (int d = 0; d < DH; ++d) s = fma(rawd[d], rawd[d], s);
    x2sh = s;
  }
  __syncthreads();

  const double tt  = (double)(*temp1p) * (double)(*tempp);
  const double tau = sqrt((double)(*tempp));
  const double x2  = x2sh;

  double bl = -INFINITY, bg = -INFINITY;
  int il = 0, ig = 0;
  for (int c = 0; c < KCB / 256; ++c) {
    const int k = c * 256 + tid;
    const float4* rp = (const float4*)(cb + k * DH);
    double dot = 0.0;
    #pragma unroll
    for (int j = 0; j < DH / 4; ++j) {
      float4 v = rp[j];
      dot = fma((double)v.x, rawd[4 * j + 0], dot);
      dot = fma((double)v.y, rawd[4 * j + 1], dot);
      dot = fma((double)v.z, rawd[4 * j + 2], dot);
      dot = fma((double)v.w, rawd[4 * j + 3], dot);
    }
    double lraw = -((x2 + c2d[k]) - 2.0 * dot);
    double zt = lraw / tt;
    if (zt > bl) { bl = zt; il = k; }
    double zg = (zt + (double)gumbel[(long long)pix * KCB + k]) / tau;
    if (zg > bg) { bg = zg; ig = k; }
  }

  const int wave = tid >> 6, lane = tid & 63;
  #pragma unroll
  for (int m = 32; m; m >>= 1) {
    double ov = __shfl_xor(bl, m, 64); int oi = __shfl_xor(il, m, 64);
    if (ov > bl || (ov == bl && oi < il)) { bl = ov; il = oi; }
    double og = __shfl_xor(bg, m, 64); int oj = __shfl_xor(ig, m, 64);
    if (og > bg || (og == bg && oj < ig)) { bg = og; ig = oj; }
  }
  if (lane == 0) { redv[0][wave] = bl; redi[0][wave] = il;
                   redv[1][wave] = bg; redi[1][wave] = ig; }
  __syncthreads();
  if (tid == 0) {
    double vl = redv[0][0], vg = redv[1][0];
    int    jl = redi[0][0], jg = redi[1][0];
    for (int w2 = 1; w2 < 4; ++w2) {
      if (redv[0][w2] > vl || (redv[0][w2] == vl && redi[0][w2] < jl)) { vl = redv[0][w2]; jl = redi[0][w2]; }
      if (redv[1][w2] > vg || (redv[1][w2] == vg && redi[1][w2] < jg)) { vg = redv[1][w2]; jg = redi[1][w2]; }
    }
    true_out[pix] = (float)jl;
    code_out[pix] = (float)jg;
    ig_sh = jg;
  }
  __syncthreads();
  if (tid < DH) quant_out[pix * DH + tid] = cb[ig_sh * DH + tid];
}

// ---------------- hard = quantized @ wq_w^T + wq_b, NCHW out ----------------
__global__ __launch_bounds__(256) void k_hard(const float* __restrict__ quant,
    const float* __restrict__ wq_w, const float* __restrict__ wq_b,
    float* __restrict__ hard) {
  __shared__ float wq[DIN * DH];
  __shared__ float qs[32][33];
  const int bh = blockIdx.x;       // b*32 + h
  const int b = bh >> 5, h = bh & 31;
  for (int idx = threadIdx.x; idx < DIN * DH; idx += 256) wq[idx] = wq_w[idx];
  for (int idx = threadIdx.x; idx < 32 * DH; idx += 256)
    qs[idx >> 5][idx & 31] = quant[bh * (32 * DH) + idx];
  __syncthreads();
  for (int it = 0; it < (DIN * 32) / 256; ++it) {
    const int idx = it * 256 + threadIdx.x;
    const int o = idx >> 5, w = idx & 31;
    float acc = wq_b[o];
    #pragma unroll
    for (int d = 0; d < DH; ++d) acc = fmaf(qs[w][d], wq[o * DH + d], acc);
    hard[((b * DIN + o) * 32 + h) * 32 + w] = acc;
  }
}

extern "C" void kernel_launch(void* const* d_in, const int* in_sizes, int n_in,
                              void* d_out, int out_size, void* d_ws, size_t ws_size,
                              hipStream_t stream) {
  const float* latent      = (const float*)d_in[0];
  const float* cb          = (const float*)d_in[1];
  const float* wv_w        = (const float*)d_in[2];
  const float* wv_b        = (const float*)d_in[3];
  const float* wq_w        = (const float*)d_in[4];
  const float* wq_b        = (const float*)d_in[5];
  const float* temp1       = (const float*)d_in[6];
  const float* gumbel      = (const float*)d_in[7];
  const int*   temperature = (const int*)d_in[8];

  float* out      = (float*)d_out;
  float* hard     = out;                 // 1572864
  float* code     = out + 1572864;       // 8192
  float* true_c   = out + 1581056;       // 8192
  float* logitRaw = out + 1589248;       // 33554432
  float* raw      = out + 35143680;      // 262144
  float* quant    = out + 35405824;      // 262144
  float* cb_out   = out + 35668096;      // 131072

  char*   ws    = (char*)d_ws;
  double* c2d   = (double*)ws;                    // 32 KB @ 0
  float*  c2f   = (float*)(ws + 32768);           // 16 KB
  int*    flags = (int*)(ws + 49152);             // 32 KB
  float*  x2f   = (float*)(ws + 81920);           // 32 KB
  float4* cbT4  = (float4*)(ws + 131072);         // 512 KB @ 128K
  float4* pl    = (float4*)(ws + 655360);         // 256 KB @ 640K
  int2*   pi    = (int2*)  (ws + 917504);         // 128 KB @ 896K (ends 1 MB)

  k_prep<<<KCB / 256, 256, 0, stream>>>(cb, c2d, c2f, cbT4);
  k_copy<<<(KCB * DH) / 256, 256, 0, stream>>>(cb, cb_out);
  k_raw <<<NPIX / 8, 256, 0, stream>>>(latent, wv_w, wv_b, raw, x2f);
  k_main<<<(NPIX / PB) * 2, 256, 0, stream>>>(raw, x2f, cbT4, c2f, gumbel,
                                              temp1, temperature, logitRaw, pl, pi);
  k_merge<<<NPIX / 8, 256, 0, stream>>>(pl, pi, cb, code, true_c, quant, flags);
  k_refine<<<NPIX, 256, 0, stream>>>(latent, wv_w, wv_b, cb, c2d, gumbel,
                                     temp1, temperature, code, true_c, quant, flags);
  k_hard<<<8 * 32, 256, 0, stream>>>(quant, wq_w, wq_b, hard);
}

// Round 15
// 144.587 us; speedup vs baseline: 1.9258x; 1.0835x over previous
//
#include <hip/hip_runtime.h>
#include <math.h>

#define NPIX 8192
#define KCB  4096
#define DH   32
#define DIN  192
#define PB   4          // pixels per k_main block: 2 in SGPR + 2 in pinned VGPR
#define EPS  2e-3f      // top-2 gap flag threshold (f32 k-dependent err <= ~4e-5)

// ---------------- prep: c2 tables + transposed codebook cbT4[8][4096] ----------------
__global__ void k_prep(const float* __restrict__ cb, double* __restrict__ c2d,
                       float* __restrict__ c2f, float4* __restrict__ cbT4) {
  int k = blockIdx.x * 256 + threadIdx.x;   // grid 16
  const float4* rp = (const float4*)(cb + k * DH);
  double s = 0.0;
  #pragma unroll
  for (int j = 0; j < DH / 4; ++j) {
    float4 v = rp[j];
    cbT4[j * KCB + k] = v;                  // coalesced transposed store
    s = fma((double)v.x, (double)v.x, s);
    s = fma((double)v.y, (double)v.y, s);
    s = fma((double)v.z, (double)v.z, s);
    s = fma((double)v.w, (double)v.w, s);
  }
  c2d[k] = s;
  c2f[k] = (float)s;
}

// ---------------- codebook passthrough ----------------
__global__ void k_copy(const float* __restrict__ src, float* __restrict__ dst) {
  int i = blockIdx.x * 256 + threadIdx.x;   // grid 512
  dst[i] = src[i];
}

// ---------------- raw = latent^T @ wv_w^T + wv_b (f32) + x2 ----------------
// grid 1024, block 256: 8 pixels/block, 32 channels per pixel group
__global__ __launch_bounds__(256) void k_raw(const float* __restrict__ latent,
    const float* __restrict__ wv_w, const float* __restrict__ wv_b,
    float* __restrict__ raw_out, float* __restrict__ x2_out) {
  __shared__ float wv[DH * 193];  // padded: conflict-free broadcast
  for (int idx = threadIdx.x; idx < DH * DIN; idx += 256) {
    int o = idx / DIN, i = idx - o * DIN;
    wv[o * 193 + i] = wv_w[idx];
  }
  __syncthreads();
  const int p = blockIdx.x * 8 + (threadIdx.x >> 5);  // pixel
  const int o = threadIdx.x & 31;
  const int b = p >> 10, hw = p & 1023;
  const float* lp = latent + b * (DIN * 1024) + hw;   // stride 1024 over channel
  float acc = wv_b[o];
  #pragma unroll 8
  for (int i = 0; i < DIN; ++i) acc = fmaf(lp[i * 1024], wv[o * 193 + i], acc);
  raw_out[p * DH + o] = acc;
  // x2 = sum_o acc^2 within the 32-lane channel group
  float s = acc * acc;
  #pragma unroll
  for (int m = 16; m; m >>= 1) s += __shfl_xor(s, m, 64);
  if (o == 0) x2_out[p] = s;
}

// monotone f32->u32 map packed with ~idx: u64 max == (max val, min idx)
__device__ inline unsigned long long packkey(float v, int idx) {
  unsigned int u = __float_as_uint(v);
  u = (u & 0x80000000u) ? ~u : (u | 0x80000000u);
  return ((unsigned long long)u << 32) | (unsigned int)(~idx);
}

__device__ inline float rfl(float x) {   // force wave-uniform (SGPR) value
  return __uint_as_float(__builtin_amdgcn_readfirstlane(__float_as_uint(x)));
}

// ---------------- main (f32): logits + top1(+top2 gap) + quantized ----------------
// grid 2048, block 256: 4 pixels/block; thread owns row k = c*256 + tid, c = 0..15
// raw: pixels 0-1 in wave-uniform SGPRs, pixels 2-3 in pinned per-thread VGPRs.
// codebook via TRANSPOSED lane-contiguous loads. No LDS in hot loop.
__global__ __launch_bounds__(256) void k_main(
    const float* __restrict__ raw_g, const float* __restrict__ x2_g,
    const float4* __restrict__ cbT4, const float* __restrict__ cb,
    const float* __restrict__ c2f, const float* __restrict__ gumbel,
    const float* __restrict__ temp1p, const int* __restrict__ tempp,
    float* __restrict__ logit_out, float* __restrict__ code_out,
    float* __restrict__ true_out, float* __restrict__ quant_out,
    int* __restrict__ flags) {
  __shared__ unsigned long long redk[2][PB][4];
  __shared__ float              redb[2][2][PB][4];  // [path][b1/b2][p][wave]
  __shared__ int code_s[PB];

  const int tid  = threadIdx.x;
  const int pix0 = blockIdx.x * PB;

  // pixels 0,1: raw -> wave-uniform scalars (SGPRs)
  float sr[2][DH];
  #pragma unroll
  for (int p = 0; p < 2; ++p)
    #pragma unroll
    for (int d = 0; d < DH; ++d)
      sr[p][d] = rfl(raw_g[(pix0 + p) * DH + d]);

  // pixels 2,3: raw -> per-thread VGPR copies (asm-pinned so they can't scalarize)
  float vr[2][DH];
  #pragma unroll
  for (int p = 0; p < 2; ++p)
    #pragma unroll
    for (int j = 0; j < DH / 4; ++j) {
      float4 t = *(const float4*)&raw_g[(pix0 + 2 + p) * DH + 4 * j];
      asm("" : "+v"(t.x), "+v"(t.y), "+v"(t.z), "+v"(t.w));
      vr[p][4 * j + 0] = t.x; vr[p][4 * j + 1] = t.y;
      vr[p][4 * j + 2] = t.z; vr[p][4 * j + 3] = t.w;
    }

  const float inv_tt = rfl((float)(1.0 / ((double)(*temp1p) * (double)(*tempp))));
  float x2r[PB];
  int   rb[PB];
  #pragma unroll
  for (int p = 0; p < PB; ++p) {
    x2r[p] = rfl(x2_g[pix0 + p]);
    rb[p]  = (pix0 + p) * KCB;
  }

  float bl[PB], bl2[PB], bg[PB], bg2[PB];
  int   bli[PB], bgi[PB];
  #pragma unroll
  for (int p = 0; p < PB; ++p) {
    bl[p] = -INFINITY; bl2[p] = -INFINITY;
    bg[p] = -INFINITY; bg2[p] = -INFINITY;
    bli[p] = 0; bgi[p] = 0;
  }

  // pipeline: gumbel + c2 for current chunk, loaded one chunk ahead
  float gfc[PB], gfn[PB];
  float c2c, c2n;
  c2c = c2f[tid];
  #pragma unroll
  for (int p = 0; p < PB; ++p) gfc[p] = gumbel[rb[p] + tid];

  #pragma unroll 1
  for (int c = 0; c < 16; ++c) {
    const int k = c * 256 + tid;               // per-thread k ascending over c

    if (c < 15) {                              // next chunk's streams in flight
      c2n = c2f[k + 256];
      #pragma unroll
      for (int p = 0; p < PB; ++p) gfn[p] = gumbel[rb[p] + k + 256];
    }

    float4 cv[8];
    #pragma unroll
    for (int j = 0; j < 8; ++j) cv[j] = cbT4[j * KCB + k];  // lane-contiguous 1KB/inst

    float dots[PB];
    #pragma unroll
    for (int p = 0; p < PB; ++p) dots[p] = 0.f;
    #pragma unroll
    for (int j = 0; j < 8; ++j) {
      // pixels 0,1: VGPR x SGPR fma
      dots[0] = fmaf(cv[j].x, sr[0][4 * j + 0], dots[0]);
      dots[0] = fmaf(cv[j].y, sr[0][4 * j + 1], dots[0]);
      dots[0] = fmaf(cv[j].z, sr[0][4 * j + 2], dots[0]);
      dots[0] = fmaf(cv[j].w, sr[0][4 * j + 3], dots[0]);
      dots[1] = fmaf(cv[j].x, sr[1][4 * j + 0], dots[1]);
      dots[1] = fmaf(cv[j].y, sr[1][4 * j + 1], dots[1]);
      dots[1] = fmaf(cv[j].z, sr[1][4 * j + 2], dots[1]);
      dots[1] = fmaf(cv[j].w, sr[1][4 * j + 3], dots[1]);
      // pixels 2,3: VGPR x VGPR fma
      dots[2] = fmaf(cv[j].x, vr[0][4 * j + 0], dots[2]);
      dots[2] = fmaf(cv[j].y, vr[0][4 * j + 1], dots[2]);
      dots[2] = fmaf(cv[j].z, vr[0][4 * j + 2], dots[2]);
      dots[2] = fmaf(cv[j].w, vr[0][4 * j + 3], dots[2]);
      dots[3] = fmaf(cv[j].x, vr[1][4 * j + 0], dots[3]);
      dots[3] = fmaf(cv[j].y, vr[1][4 * j + 1], dots[3]);
      dots[3] = fmaf(cv[j].z, vr[1][4 * j + 2], dots[3]);
      dots[3] = fmaf(cv[j].w, vr[1][4 * j + 3], dots[3]);
    }

    #pragma unroll
    for (int p = 0; p < PB; ++p) {
      float v = fmaf(2.f, dots[p], -(x2r[p] + c2c));
      __builtin_nontemporal_store(v, &logit_out[rb[p] + k]);
      bool bt = v > bl[p];
      bl2[p] = bt ? bl[p] : fmaxf(bl2[p], v);
      bli[p] = bt ? k : bli[p];
      bl[p]  = bt ? v : bl[p];
      float z = fmaf(v, inv_tt, gfc[p]);        // gumbel prefetched last chunk
      bool gt = z > bg[p];
      bg2[p] = gt ? bg[p] : fmaxf(bg2[p], z);
      bgi[p] = gt ? k : bgi[p];
      bg[p]  = gt ? z : bg[p];
    }

    c2c = c2n;
    #pragma unroll
    for (int p = 0; p < PB; ++p) gfc[p] = gfn[p];
  }

  // block reduction: 64-lane butterfly of (top1-key, top1-val, top2-val), then LDS
  const int wave = tid >> 6;
  const int lane = tid & 63;
  #pragma unroll
  for (int p = 0; p < PB; ++p) {
    unsigned long long kl = packkey(bl[p], bli[p]);
    unsigned long long kg = packkey(bg[p], bgi[p]);
    float b1l = bl[p], b2l = bl2[p], b1g = bg[p], b2g = bg2[p];
    #pragma unroll
    for (int m = 32; m; m >>= 1) {
      unsigned long long o1 = __shfl_xor(kl, m, 64);
      float ob1 = __shfl_xor(b1l, m, 64), ob2 = __shfl_xor(b2l, m, 64);
      b2l = fmaxf(fmaxf(b2l, ob2), fminf(b1l, ob1));
      b1l = fmaxf(b1l, ob1);
      if (o1 > kl) kl = o1;
      unsigned long long o2 = __shfl_xor(kg, m, 64);
      float og1 = __shfl_xor(b1g, m, 64), og2 = __shfl_xor(b2g, m, 64);
      b2g = fmaxf(fmaxf(b2g, og2), fminf(b1g, og1));
      b1g = fmaxf(b1g, og1);
      if (o2 > kg) kg = o2;
    }
    if (lane == 0) {
      redk[0][p][wave] = kl;  redk[1][p][wave] = kg;
      redb[0][0][p][wave] = b1l; redb[0][1][p][wave] = b2l;
      redb[1][0][p][wave] = b1g; redb[1][1][p][wave] = b2g;
    }
  }
  __syncthreads();
  if (tid < PB) {
    const int p = tid;
    unsigned long long kl = redk[0][p][0], kg = redk[1][p][0];
    float b1l = redb[0][0][p][0], b2l = redb[0][1][p][0];
    float b1g = redb[1][0][p][0], b2g = redb[1][1][p][0];
    #pragma unroll
    for (int w2 = 1; w2 < 4; ++w2) {
      if (redk[0][p][w2] > kl) kl = redk[0][p][w2];
      if (redk[1][p][w2] > kg) kg = redk[1][p][w2];
      b2l = fmaxf(fmaxf(b2l, redb[0][1][p][w2]), fminf(b1l, redb[0][0][p][w2]));
      b1l = fmaxf(b1l, redb[0][0][p][w2]);
      b2g = fmaxf(fmaxf(b2g, redb[1][1][p][w2]), fminf(b1g, redb[1][0][p][w2]));
      b1g = fmaxf(b1g, redb[1][0][p][w2]);
    }
    int ti = (int)(~(unsigned int)kl);
    int ci = (int)(~(unsigned int)kg);
    true_out[pix0 + p] = (float)ti;
    code_out[pix0 + p] = (float)ci;
    code_s[p] = ci;
    flags[pix0 + p] = (b1l - b2l < EPS || b1g - b2g < EPS) ? 1 : 0;
  }
  __syncthreads();
  if (tid < PB * DH)
    quant_out[pix0 * DH + tid] = cb[code_s[tid >> 5] * DH + (tid & 31)];
}

// ---------------- refine (exact f64, flagged pixels only; rare) ----------------
// grid 8192, block 256; unflagged blocks exit immediately
__global__ __launch_bounds__(256) void k_refine(
    const float* __restrict__ latent, const float* __restrict__ wv_w,
    const float* __restrict__ wv_b, const float* __restrict__ cb,
    const double* __restrict__ c2d, const float* __restrict__ gumbel,
    const float* __restrict__ temp1p, const int* __restrict__ tempp,
    float* __restrict__ code_out, float* __restrict__ true_out,
    float* __restrict__ quant_out, const int* __restrict__ flags) {
  const int pix = blockIdx.x;
  if (flags[pix] == 0) return;

  __shared__ double part[DH][8];
  __shared__ double rawd[DH];
  __shared__ double x2sh;
  __shared__ double redv[2][4];
  __shared__ int    redi[2][4];
  __shared__ int    ig_sh;
  const int tid = threadIdx.x;
  const int b = pix >> 10, hw = pix & 1023;

  // raw: 32 channels x 8 partials (24 terms each)
  {
    const int o = tid >> 3, pt = tid & 7;
    const float* lp = latent + b * (DIN * 1024) + hw;
    double acc = 0.0;
    #pragma unroll 4
    for (int i = pt * 24; i < pt * 24 + 24; ++i)
      acc = fma((double)lp[i * 1024], (double)wv_w[o * DIN + i], acc);
    part[o][pt] = acc;
  }
  __syncthreads();
  if (tid < DH) {
    double acc = (double)wv_b[tid];
    #pragma unroll
    for (int j = 0; j < 8; ++j) acc += part[tid][j];
    rawd[tid] = acc;
  }
  __syncthreads();
  if (tid == 0) {
    double s = 0.0;
    #pragma unroll
    for (int d = 0; d < DH; ++d) s = fma(rawd[d], rawd[d], s);
    x2sh = s;
  }
  __syncthreads();

  const double tt  = (double)(*temp1p) * (double)(*tempp);
  const double tau = sqrt((double)(*tempp));
  const double x2  = x2sh;

  double bl = -INFINITY, bg = -INFINITY;
  int il = 0, ig = 0;
  for (int c = 0; c < KCB / 256; ++c) {
    const int k = c * 256 + tid;            // per-thread k ascending
    const float4* rp = (const float4*)(cb + k * DH);
    double dot = 0.0;
    #pragma unroll
    for (int j = 0; j < DH / 4; ++j) {
      float4 v = rp[j];
      dot = fma((double)v.x, rawd[4 * j + 0], dot);
      dot = fma((double)v.y, rawd[4 * j + 1], dot);
      dot = fma((double)v.z, rawd[4 * j + 2], dot);
      dot = fma((double)v.w, rawd[4 * j + 3], dot);
    }
    double lraw = -((x2 + c2d[k]) - 2.0 * dot);
    double zt = lraw / tt;
    if (zt > bl) { bl = zt; il = k; }
    double zg = (zt + (double)gumbel[(long long)pix * KCB + k]) / tau;
    if (zg > bg) { bg = zg; ig = k; }
  }

  const int wave = tid >> 6, lane = tid & 63;
  #pragma unroll
  for (int m = 32; m; m >>= 1) {
    double ov = __shfl_xor(bl, m, 64); int oi = __shfl_xor(il, m, 64);
    if (ov > bl || (ov == bl && oi < il)) { bl = ov; il = oi; }
    double og = __shfl_xor(bg, m, 64); int oj = __shfl_xor(ig, m, 64);
    if (og > bg || (og == bg && oj < ig)) { bg = og; ig = oj; }
  }
  if (lane == 0) { redv[0][wave] = bl; redi[0][wave] = il;
                   redv[1][wave] = bg; redi[1][wave] = ig; }
  __syncthreads();
  if (tid == 0) {
    double vl = redv[0][0], vg = redv[1][0];
    int    jl = redi[0][0], jg = redi[1][0];
    for (int w2 = 1; w2 < 4; ++w2) {
      if (redv[0][w2] > vl || (redv[0][w2] == vl && redi[0][w2] < jl)) { vl = redv[0][w2]; jl = redi[0][w2]; }
      if (redv[1][w2] > vg || (redv[1][w2] == vg && redi[1][w2] < jg)) { vg = redv[1][w2]; jg = redi[1][w2]; }
    }
    true_out[pix] = (float)jl;
    code_out[pix] = (float)jg;
    ig_sh = jg;
  }
  __syncthreads();
  if (tid < DH) quant_out[pix * DH + tid] = cb[ig_sh * DH + tid];
}

// ---------------- hard = quantized @ wq_w^T + wq_b, NCHW out ----------------
__global__ __launch_bounds__(256) void k_hard(const float* __restrict__ quant,
    const float* __restrict__ wq_w, const float* __restrict__ wq_b,
    float* __restrict__ hard) {
  __shared__ float wq[DIN * DH];
  __shared__ float qs[32][33];
  const int bh = blockIdx.x;       // b*32 + h
  const int b = bh >> 5, h = bh & 31;
  for (int idx = threadIdx.x; idx < DIN * DH; idx += 256) wq[idx] = wq_w[idx];
  for (int idx = threadIdx.x; idx < 32 * DH; idx += 256)
    qs[idx >> 5][idx & 31] = quant[bh * (32 * DH) + idx];
  __syncthreads();
  for (int it = 0; it < (DIN * 32) / 256; ++it) {
    const int idx = it * 256 + threadIdx.x;
    const int o = idx >> 5, w = idx & 31;
    float acc = wq_b[o];
    #pragma unroll
    for (int d = 0; d < DH; ++d) acc = fmaf(qs[w][d], wq[o * DH + d], acc);
    hard[((b * DIN + o) * 32 + h) * 32 + w] = acc;
  }
}

extern "C" void kernel_launch(void* const* d_in, const int* in_sizes, int n_in,
                              void* d_out, int out_size, void* d_ws, size_t ws_size,
                              hipStream_t stream) {
  const float* latent      = (const float*)d_in[0];
  const float* cb          = (const float*)d_in[1];
  const float* wv_w        = (const float*)d_in[2];
  const float* wv_b        = (const float*)d_in[3];
  const float* wq_w        = (const float*)d_in[4];
  const float* wq_b        = (const float*)d_in[5];
  const float* temp1       = (const float*)d_in[6];
  const float* gumbel      = (const float*)d_in[7];
  const int*   temperature = (const int*)d_in[8];

  float* out      = (float*)d_out;
  float* hard     = out;                 // 1572864
  float* code     = out + 1572864;       // 8192
  float* true_c   = out + 1581056;       // 8192
  float* logitRaw = out + 1589248;       // 33554432
  float* raw      = out + 35143680;      // 262144
  float* quant    = out + 35405824;      // 262144
  float* cb_out   = out + 35668096;      // 131072

  char*   ws    = (char*)d_ws;
  double* c2d   = (double*)ws;                    // 32 KB @ 0
  float*  c2f   = (float*)(ws + 32768);           // 16 KB
  int*    flags = (int*)(ws + 49152);             // 32 KB
  float*  x2f   = (float*)(ws + 81920);           // 32 KB
  float4* cbT4  = (float4*)(ws + 131072);         // 512 KB @ 128K

  k_prep<<<KCB / 256, 256, 0, stream>>>(cb, c2d, c2f, cbT4);
  k_copy<<<(KCB * DH) / 256, 256, 0, stream>>>(cb, cb_out);
  k_raw <<<NPIX / 8, 256, 0, stream>>>(latent, wv_w, wv_b, raw, x2f);
  k_main<<<NPIX / PB, 256, 0, stream>>>(raw, x2f, cbT4, cb, c2f, gumbel,
                                        temp1, temperature, logitRaw,
                                        code, true_c, quant, flags);
  k_refine<<<NPIX, 256, 0, stream>>>(latent, wv_w, wv_b, cb, c2d, gumbel,
                                     temp1, temperature, code, true_c, quant, flags);
  k_hard<<<8 * 32, 256, 0, stream>>>(quant, wq_w, wq_b, hard);
}

// Round 16
// 142.528 us; speedup vs baseline: 1.9536x; 1.0144x over previous
//
#include <hip/hip_runtime.h>
#include <math.h>

#define NPIX 8192
#define KCB  4096
#define DH   32
#define DIN  192
#define PB   4          // pixels per k_main block: 2 in SGPR + 2 in pinned VGPR
#define EPS  2e-3f      // top-2 gap flag threshold (f32 k-dependent err <= ~4e-5)

// ---------------- prep: c2 tables + transposed codebook + cb passthrough ----------------
__global__ void k_prep(const float* __restrict__ cb, double* __restrict__ c2d,
                       float* __restrict__ c2f, float4* __restrict__ cbT4,
                       float4* __restrict__ cb_out4) {
  int k = blockIdx.x * 256 + threadIdx.x;   // grid 16
  const float4* rp = (const float4*)(cb + k * DH);
  double s = 0.0;
  #pragma unroll
  for (int j = 0; j < DH / 4; ++j) {
    float4 v = rp[j];
    cbT4[j * KCB + k] = v;                  // coalesced transposed store
    cb_out4[k * (DH / 4) + j] = v;          // fused codebook passthrough output
    s = fma((double)v.x, (double)v.x, s);
    s = fma((double)v.y, (double)v.y, s);
    s = fma((double)v.z, (double)v.z, s);
    s = fma((double)v.w, (double)v.w, s);
  }
  c2d[k] = s;
  c2f[k] = (float)s;
}

// ---------------- raw = latent^T @ wv_w^T + wv_b (f32) + x2 ----------------
// grid 1024, block 256: 8 pixels/block, 32 channels per pixel group
__global__ __launch_bounds__(256) void k_raw(const float* __restrict__ latent,
    const float* __restrict__ wv_w, const float* __restrict__ wv_b,
    float* __restrict__ raw_out, float* __restrict__ x2_out) {
  __shared__ float wv[DH * 193];  // padded: conflict-free broadcast
  for (int idx = threadIdx.x; idx < DH * DIN; idx += 256) {
    int o = idx / DIN, i = idx - o * DIN;
    wv[o * 193 + i] = wv_w[idx];
  }
  __syncthreads();
  const int p = blockIdx.x * 8 + (threadIdx.x >> 5);  // pixel
  const int o = threadIdx.x & 31;
  const int b = p >> 10, hw = p & 1023;
  const float* lp = latent + b * (DIN * 1024) + hw;   // stride 1024 over channel
  float acc = wv_b[o];
  #pragma unroll 8
  for (int i = 0; i < DIN; ++i) acc = fmaf(lp[i * 1024], wv[o * 193 + i], acc);
  raw_out[p * DH + o] = acc;
  // x2 = sum_o acc^2 within the 32-lane channel group
  float s = acc * acc;
  #pragma unroll
  for (int m = 16; m; m >>= 1) s += __shfl_xor(s, m, 64);
  if (o == 0) x2_out[p] = s;
}

// monotone f32->u32 map packed with ~idx: u64 max == (max val, min idx)
__device__ inline unsigned long long packkey(float v, int idx) {
  unsigned int u = __float_as_uint(v);
  u = (u & 0x80000000u) ? ~u : (u | 0x80000000u);
  return ((unsigned long long)u << 32) | (unsigned int)(~idx);
}

__device__ inline float rfl(float x) {   // force wave-uniform (SGPR) value
  return __uint_as_float(__builtin_amdgcn_readfirstlane(__float_as_uint(x)));
}

// ---------------- main (f32): logits + top1(+top2 gap) + quantized ----------------
// grid 2048, block 256: 4 pixels/block; thread owns row k = c*256 + tid, c = 0..15
// raw: pixels 0-1 in wave-uniform SGPRs, pixels 2-3 in pinned per-thread VGPRs.
// codebook via TRANSPOSED lane-contiguous loads. No LDS in hot loop.
__global__ __launch_bounds__(256) void k_main(
    const float* __restrict__ raw_g, const float* __restrict__ x2_g,
    const float4* __restrict__ cbT4, const float* __restrict__ cb,
    const float* __restrict__ c2f, const float* __restrict__ gumbel,
    const float* __restrict__ temp1p, const int* __restrict__ tempp,
    float* __restrict__ logit_out, float* __restrict__ code_out,
    float* __restrict__ true_out, float* __restrict__ quant_out,
    int* __restrict__ flags) {
  __shared__ unsigned long long redk[2][PB][4];
  __shared__ float              redb[2][2][PB][4];  // [path][b1/b2][p][wave]
  __shared__ int code_s[PB];

  const int tid  = threadIdx.x;
  const int pix0 = blockIdx.x * PB;

  // pixels 0,1: raw -> wave-uniform scalars (SGPRs)
  float sr[2][DH];
  #pragma unroll
  for (int p = 0; p < 2; ++p)
    #pragma unroll
    for (int d = 0; d < DH; ++d)
      sr[p][d] = rfl(raw_g[(pix0 + p) * DH + d]);

  // pixels 2,3: raw -> per-thread VGPR copies (asm-pinned so they can't scalarize)
  float vr[2][DH];
  #pragma unroll
  for (int p = 0; p < 2; ++p)
    #pragma unroll
    for (int j = 0; j < DH / 4; ++j) {
      float4 t = *(const float4*)&raw_g[(pix0 + 2 + p) * DH + 4 * j];
      asm("" : "+v"(t.x), "+v"(t.y), "+v"(t.z), "+v"(t.w));
      vr[p][4 * j + 0] = t.x; vr[p][4 * j + 1] = t.y;
      vr[p][4 * j + 2] = t.z; vr[p][4 * j + 3] = t.w;
    }

  const float inv_tt = rfl((float)(1.0 / ((double)(*temp1p) * (double)(*tempp))));
  float x2r[PB];
  int   rb[PB];
  #pragma unroll
  for (int p = 0; p < PB; ++p) {
    x2r[p] = rfl(x2_g[pix0 + p]);
    rb[p]  = (pix0 + p) * KCB;
  }

  float bl[PB], bl2[PB], bg[PB], bg2[PB];
  int   bli[PB], bgi[PB];
  #pragma unroll
  for (int p = 0; p < PB; ++p) {
    bl[p] = -INFINITY; bl2[p] = -INFINITY;
    bg[p] = -INFINITY; bg2[p] = -INFINITY;
    bli[p] = 0; bgi[p] = 0;
  }

  // pipeline: gumbel + c2 for current chunk, loaded one chunk ahead
  float gfc[PB], gfn[PB];
  float c2c, c2n;
  c2c = c2f[tid];
  #pragma unroll
  for (int p = 0; p < PB; ++p) gfc[p] = gumbel[rb[p] + tid];

  #pragma unroll 1
  for (int c = 0; c < 16; ++c) {
    const int k = c * 256 + tid;               // per-thread k ascending over c

    if (c < 15) {                              // next chunk's streams in flight
      c2n = c2f[k + 256];
      #pragma unroll
      for (int p = 0; p < PB; ++p) gfn[p] = gumbel[rb[p] + k + 256];
    }

    float4 cv[8];
    #pragma unroll
    for (int j = 0; j < 8; ++j) cv[j] = cbT4[j * KCB + k];  // lane-contiguous 1KB/inst

    float dots[PB];
    #pragma unroll
    for (int p = 0; p < PB; ++p) dots[p] = 0.f;
    #pragma unroll
    for (int j = 0; j < 8; ++j) {
      // pixels 0,1: VGPR x SGPR fma
      dots[0] = fmaf(cv[j].x, sr[0][4 * j + 0], dots[0]);
      dots[0] = fmaf(cv[j].y, sr[0][4 * j + 1], dots[0]);
      dots[0] = fmaf(cv[j].z, sr[0][4 * j + 2], dots[0]);
      dots[0] = fmaf(cv[j].w, sr[0][4 * j + 3], dots[0]);
      dots[1] = fmaf(cv[j].x, sr[1][4 * j + 0], dots[1]);
      dots[1] = fmaf(cv[j].y, sr[1][4 * j + 1], dots[1]);
      dots[1] = fmaf(cv[j].z, sr[1][4 * j + 2], dots[1]);
      dots[1] = fmaf(cv[j].w, sr[1][4 * j + 3], dots[1]);
      // pixels 2,3: VGPR x VGPR fma
      dots[2] = fmaf(cv[j].x, vr[0][4 * j + 0], dots[2]);
      dots[2] = fmaf(cv[j].y, vr[0][4 * j + 1], dots[2]);
      dots[2] = fmaf(cv[j].z, vr[0][4 * j + 2], dots[2]);
      dots[2] = fmaf(cv[j].w, vr[0][4 * j + 3], dots[2]);
      dots[3] = fmaf(cv[j].x, vr[1][4 * j + 0], dots[3]);
      dots[3] = fmaf(cv[j].y, vr[1][4 * j + 1], dots[3]);
      dots[3] = fmaf(cv[j].z, vr[1][4 * j + 2], dots[3]);
      dots[3] = fmaf(cv[j].w, vr[1][4 * j + 3], dots[3]);
    }

    #pragma unroll
    for (int p = 0; p < PB; ++p) {
      float v = fmaf(2.f, dots[p], -(x2r[p] + c2c));
      __builtin_nontemporal_store(v, &logit_out[rb[p] + k]);
      bool bt = v > bl[p];
      bl2[p] = bt ? bl[p] : fmaxf(bl2[p], v);
      bli[p] = bt ? k : bli[p];
      bl[p]  = bt ? v : bl[p];
      float z = fmaf(v, inv_tt, gfc[p]);        // gumbel prefetched last chunk
      bool gt = z > bg[p];
      bg2[p] = gt ? bg[p] : fmaxf(bg2[p], z);
      bgi[p] = gt ? k : bgi[p];
      bg[p]  = gt ? z : bg[p];
    }

    c2c = c2n;
    #pragma unroll
    for (int p = 0; p < PB; ++p) gfc[p] = gfn[p];
  }

  // block reduction: 64-lane butterfly of (top1-key, top1-val, top2-val), then LDS
  const int wave = tid >> 6;
  const int lane = tid & 63;
  #pragma unroll
  for (int p = 0; p < PB; ++p) {
    unsigned long long kl = packkey(bl[p], bli[p]);
    unsigned long long kg = packkey(bg[p], bgi[p]);
    float b1l = bl[p], b2l = bl2[p], b1g = bg[p], b2g = bg2[p];
    #pragma unroll
    for (int m = 32; m; m >>= 1) {
      unsigned long long o1 = __shfl_xor(kl, m, 64);
      float ob1 = __shfl_xor(b1l, m, 64), ob2 = __shfl_xor(b2l, m, 64);
      b2l = fmaxf(fmaxf(b2l, ob2), fminf(b1l, ob1));
      b1l = fmaxf(b1l, ob1);
      if (o1 > kl) kl = o1;
      unsigned long long o2 = __shfl_xor(kg, m, 64);
      float og1 = __shfl_xor(b1g, m, 64), og2 = __shfl_xor(b2g, m, 64);
      b2g = fmaxf(fmaxf(b2g, og2), fminf(b1g, og1));
      b1g = fmaxf(b1g, og1);
      if (o2 > kg) kg = o2;
    }
    if (lane == 0) {
      redk[0][p][wave] = kl;  redk[1][p][wave] = kg;
      redb[0][0][p][wave] = b1l; redb[0][1][p][wave] = b2l;
      redb[1][0][p][wave] = b1g; redb[1][1][p][wave] = b2g;
    }
  }
  __syncthreads();
  if (tid < PB) {
    const int p = tid;
    unsigned long long kl = redk[0][p][0], kg = redk[1][p][0];
    float b1l = redb[0][0][p][0], b2l = redb[0][1][p][0];
    float b1g = redb[1][0][p][0], b2g = redb[1][1][p][0];
    #pragma unroll
    for (int w2 = 1; w2 < 4; ++w2) {
      if (redk[0][p][w2] > kl) kl = redk[0][p][w2];
      if (redk[1][p][w2] > kg) kg = redk[1][p][w2];
      b2l = fmaxf(fmaxf(b2l, redb[0][1][p][w2]), fminf(b1l, redb[0][0][p][w2]));
      b1l = fmaxf(b1l, redb[0][0][p][w2]);
      b2g = fmaxf(fmaxf(b2g, redb[1][1][p][w2]), fminf(b1g, redb[1][0][p][w2]));
      b1g = fmaxf(b1g, redb[1][0][p][w2]);
    }
    int ti = (int)(~(unsigned int)kl);
    int ci = (int)(~(unsigned int)kg);
    true_out[pix0 + p] = (float)ti;
    code_out[pix0 + p] = (float)ci;
    code_s[p] = ci;
    flags[pix0 + p] = (b1l - b2l < EPS || b1g - b2g < EPS) ? 1 : 0;
  }
  __syncthreads();
  if (tid < PB * DH)
    quant_out[pix0 * DH + tid] = cb[code_s[tid >> 5] * DH + (tid & 31)];
}

// ---------------- refine (exact f64, flagged pixels only; rare) ----------------
// grid 8192, block 256; unflagged blocks exit immediately
__global__ __launch_bounds__(256) void k_refine(
    const float* __restrict__ latent, const float* __restrict__ wv_w,
    const float* __restrict__ wv_b, const float* __restrict__ cb,
    const double* __restrict__ c2d, const float* __restrict__ gumbel,
    const float* __restrict__ temp1p, const int* __restrict__ tempp,
    float* __restrict__ code_out, float* __restrict__ true_out,
    float* __restrict__ quant_out, const int* __restrict__ flags) {
  const int pix = blockIdx.x;
  if (flags[pix] == 0) return;

  __shared__ double part[DH][8];
  __shared__ double rawd[DH];
  __shared__ double x2sh;
  __shared__ double redv[2][4];
  __shared__ int    redi[2][4];
  __shared__ int    ig_sh;
  const int tid = threadIdx.x;
  const int b = pix >> 10, hw = pix & 1023;

  // raw: 32 channels x 8 partials (24 terms each)
  {
    const int o = tid >> 3, pt = tid & 7;
    const float* lp = latent + b * (DIN * 1024) + hw;
    double acc = 0.0;
    #pragma unroll 4
    for (int i = pt * 24; i < pt * 24 + 24; ++i)
      acc = fma((double)lp[i * 1024], (double)wv_w[o * DIN + i], acc);
    part[o][pt] = acc;
  }
  __syncthreads();
  if (tid < DH) {
    double acc = (double)wv_b[tid];
    #pragma unroll
    for (int j = 0; j < 8; ++j) acc += part[tid][j];
    rawd[tid] = acc;
  }
  __syncthreads();
  if (tid == 0) {
    double s = 0.0;
    #pragma unroll
    for (int d = 0; d < DH; ++d) s = fma(rawd[d], rawd[d], s);
    x2sh = s;
  }
  __syncthreads();

  const double tt  = (double)(*temp1p) * (double)(*tempp);
  const double tau = sqrt((double)(*tempp));
  const double x2  = x2sh;

  double bl = -INFINITY, bg = -INFINITY;
  int il = 0, ig = 0;
  for (int c = 0; c < KCB / 256; ++c) {
    const int k = c * 256 + tid;            // per-thread k ascending
    const float4* rp = (const float4*)(cb + k * DH);
    double dot = 0.0;
    #pragma unroll
    for (int j = 0; j < DH / 4; ++j) {
      float4 v = rp[j];
      dot = fma((double)v.x, rawd[4 * j + 0], dot);
      dot = fma((double)v.y, rawd[4 * j + 1], dot);
      dot = fma((double)v.z, rawd[4 * j + 2], dot);
      dot = fma((double)v.w, rawd[4 * j + 3], dot);
    }
    double lraw = -((x2 + c2d[k]) - 2.0 * dot);
    double zt = lraw / tt;
    if (zt > bl) { bl = zt; il = k; }
    double zg = (zt + (double)gumbel[(long long)pix * KCB + k]) / tau;
    if (zg > bg) { bg = zg; ig = k; }
  }

  const int wave = tid >> 6, lane = tid & 63;
  #pragma unroll
  for (int m = 32; m; m >>= 1) {
    double ov = __shfl_xor(bl, m, 64); int oi = __shfl_xor(il, m, 64);
    if (ov > bl || (ov == bl && oi < il)) { bl = ov; il = oi; }
    double og = __shfl_xor(bg, m, 64); int oj = __shfl_xor(ig, m, 64);
    if (og > bg || (og == bg && oj < ig)) { bg = og; ig = oj; }
  }
  if (lane == 0) { redv[0][wave] = bl; redi[0][wave] = il;
                   redv[1][wave] = bg; redi[1][wave] = ig; }
  __syncthreads();
  if (tid == 0) {
    double vl = redv[0][0], vg = redv[1][0];
    int    jl = redi[0][0], jg = redi[1][0];
    for (int w2 = 1; w2 < 4; ++w2) {
      if (redv[0][w2] > vl || (redv[0][w2] == vl && redi[0][w2] < jl)) { vl = redv[0][w2]; jl = redi[0][w2]; }
      if (redv[1][w2] > vg || (redv[1][w2] == vg && redi[1][w2] < jg)) { vg = redv[1][w2]; jg = redi[1][w2]; }
    }
    true_out[pix] = (float)jl;
    code_out[pix] = (float)jg;
    ig_sh = jg;
  }
  __syncthreads();
  if (tid < DH) quant_out[pix * DH + tid] = cb[ig_sh * DH + tid];
}

// ---------------- hard = quantized @ wq_w^T + wq_b, NCHW out ----------------
__global__ __launch_bounds__(256) void k_hard(const float* __restrict__ quant,
    const float* __restrict__ wq_w, const float* __restrict__ wq_b,
    float* __restrict__ hard) {
  __shared__ float wq[DIN * DH];
  __shared__ float qs[32][33];
  const int bh = blockIdx.x;       // b*32 + h
  const int b = bh >> 5, h = bh & 31;
  for (int idx = threadIdx.x; idx < DIN * DH; idx += 256) wq[idx] = wq_w[idx];
  for (int idx = threadIdx.x; idx < 32 * DH; idx += 256)
    qs[idx >> 5][idx & 31] = quant[bh * (32 * DH) + idx];
  __syncthreads();
  for (int it = 0; it < (DIN * 32) / 256; ++it) {
    const int idx = it * 256 + threadIdx.x;
    const int o = idx >> 5, w = idx & 31;
    float acc = wq_b[o];
    #pragma unroll
    for (int d = 0; d < DH; ++d) acc = fmaf(qs[w][d], wq[o * DH + d], acc);
    hard[((b * DIN + o) * 32 + h) * 32 + w] = acc;
  }
}

extern "C" void kernel_launch(void* const* d_in, const int* in_sizes, int n_in,
                              void* d_out, int out_size, void* d_ws, size_t ws_size,
                              hipStream_t stream) {
  const float* latent      = (const float*)d_in[0];
  const float* cb          = (const float*)d_in[1];
  const float* wv_w        = (const float*)d_in[2];
  const float* wv_b        = (const float*)d_in[3];
  const float* wq_w        = (const float*)d_in[4];
  const float* wq_b        = (const float*)d_in[5];
  const float* temp1       = (const float*)d_in[6];
  const float* gumbel      = (const float*)d_in[7];
  const int*   temperature = (const int*)d_in[8];

  float* out      = (float*)d_out;
  float* hard     = out;                 // 1572864
  float* code     = out + 1572864;       // 8192
  float* true_c   = out + 1581056;       // 8192
  float* logitRaw = out + 1589248;       // 33554432
  float* raw      = out + 35143680;      // 262144
  float* quant    = out + 35405824;      // 262144
  float* cb_out   = out + 35668096;      // 131072

  char*   ws    = (char*)d_ws;
  double* c2d   = (double*)ws;                    // 32 KB @ 0
  float*  c2f   = (float*)(ws + 32768);           // 16 KB
  int*    flags = (int*)(ws + 49152);             // 32 KB
  float*  x2f   = (float*)(ws + 81920);           // 32 KB
  float4* cbT4  = (float4*)(ws + 131072);         // 512 KB @ 128K

  k_prep<<<KCB / 256, 256, 0, stream>>>(cb, c2d, c2f, cbT4, (float4*)cb_out);
  k_raw <<<NPIX / 8, 256, 0, stream>>>(latent, wv_w, wv_b, raw, x2f);
  k_main<<<NPIX / PB, 256, 0, stream>>>(raw, x2f, cbT4, cb, c2f, gumbel,
                                        temp1, temperature, logitRaw,
                                        code, true_c, quant, flags);
  k_refine<<<NPIX, 256, 0, stream>>>(latent, wv_w, wv_b, cb, c2d, gumbel,
                                     temp1, temperature, code, true_c, quant, flags);
  k_hard<<<8 * 32, 256, 0, stream>>>(quant, wq_w, wq_b, hard);
}